// Round 1
// baseline (250.734 us; speedup 1.0000x reference)
//
#include <hip/hip_runtime.h>
#include <hip/hip_bf16.h>
#include <math.h>

#define NJ 24
#define NV 6890
#define NVP 6912          // padded vertex count (27*256)
#define NPRIME 20736      // 3*NVP, GEMM N dimension
#define NT 1296           // NPRIME/16 n-tiles
#define KDIM 224          // padded K: [0..9]=betas/sd, [10]=1/vt, [11..217]=lrot/pd, rest 0

__constant__ int c_par[24] = {0, 0, 0, 0, 1, 2, 3, 4, 5, 6, 7, 8, 9, 9, 9,
                              12, 13, 14, 16, 17, 18, 19, 20, 21};

typedef __attribute__((ext_vector_type(8))) short short8;
typedef __attribute__((ext_vector_type(4))) float float4v;

__device__ __forceinline__ unsigned short f2b(float x) {
    __hip_bfloat16 h = __float2bfloat16(x);
    return *reinterpret_cast<unsigned short*>(&h);
}
__device__ __forceinline__ float b2f(unsigned short u) {
    unsigned int w = ((unsigned int)u) << 16;
    return __uint_as_float(w);
}

// ---------------------------------------------------------------------------
// T: pack kernel.
//  B2  : MFMA-tiled bf16 B''[kc][nt][ln16][kk32]; element (k, n'=c*NVP+v):
//        k<10 -> sd[v][c][k]; k==10 -> vt[v][c]; 11<=k<218 -> pd[v][c][k-11]; else 0.
//        Consecutive elements <-> consecutive p: reads AND writes coalesced.
//  w_t / jr_t : f32 [24][NVP];  sd_t: f32 [30][NVP]; vt_t: f32 [3][NVP]
__global__ void t_pack(const float* __restrict__ pd,
                       const float* __restrict__ W,
                       const float* __restrict__ jr,
                       const float* __restrict__ sd,
                       const float* __restrict__ vt,
                       unsigned short* __restrict__ B2,
                       float* __restrict__ w_t,
                       float* __restrict__ jr_t,
                       float* __restrict__ sd_t,
                       float* __restrict__ vt_t) {
    int idx = blockIdx.x * 256 + threadIdx.x;
    const int B2_N = 7 * NT * 16 * 32;        // 4,644,864
    if (idx < B2_N) {
        int kk = idx & 31;
        int ln = (idx >> 5) & 15;
        int rest = idx >> 9;                  // nt + NT*kc
        int nt = rest % NT, kc = rest / NT;
        int k = kc * 32 + kk;
        int np = nt * 16 + ln;
        int c = np / NVP, v = np - c * NVP;
        float val = 0.f;
        if (v < NV) {
            if (k < 10)       val = sd[(size_t)v * 30 + c * 10 + k];
            else if (k == 10) val = vt[v * 3 + c];
            else if (k < 218) val = pd[(size_t)v * 621 + c * 207 + (k - 11)];
        }
        B2[idx] = f2b(val);
        return;
    }
    idx -= B2_N;
    if (idx < 24 * NVP) {
        int j = idx / NVP, v = idx % NVP;
        if (v < NV) w_t[(size_t)j * NVP + v] = W[(size_t)v * 24 + j];
        return;
    }
    idx -= 24 * NVP;
    if (idx < 24 * NVP) {
        int j = idx / NVP, v = idx % NVP;
        if (v < NV) jr_t[(size_t)j * NVP + v] = jr[(size_t)v * 24 + j];
        return;
    }
    idx -= 24 * NVP;
    if (idx < 30 * NVP) {
        int r = idx / NVP, v = idx % NVP;
        if (v < NV) sd_t[(size_t)r * NVP + v] = sd[(size_t)v * 30 + r];
        return;
    }
    idx -= 30 * NVP;
    if (idx < 3 * NVP) {
        int c = idx / NVP, v = idx % NVP;
        if (v < NV) vt_t[(size_t)c * NVP + v] = vt[(size_t)v * 3 + c];
    }
}

// ---------------------------------------------------------------------------
// K1: fold J_regressor into shapedirs / v_template (coalesced, fp32).
__global__ void k1_regress(const float* __restrict__ Jreg,
                           const float* __restrict__ sd_t,
                           const float* __restrict__ vt_t,
                           float* __restrict__ SD_J,
                           float* __restrict__ Jt) {
    int j = blockIdx.x / 3;
    int c = blockIdx.x % 3;
    float acc[11];
#pragma unroll
    for (int k = 0; k < 11; k++) acc[k] = 0.f;

    for (int v = threadIdx.x; v < NV; v += 256) {
        float r = Jreg[j * NV + v];
#pragma unroll
        for (int k = 0; k < 10; k++)
            acc[k] += r * sd_t[(size_t)(c * 10 + k) * NVP + v];
        acc[10] += r * vt_t[(size_t)c * NVP + v];
    }
#pragma unroll
    for (int k = 0; k < 11; k++) {
        float x = acc[k];
        for (int off = 32; off > 0; off >>= 1) x += __shfl_down(x, off);
        acc[k] = x;
    }
    __shared__ float red[4][11];
    int lane = threadIdx.x & 63, wid = threadIdx.x >> 6;
    if (lane == 0) {
#pragma unroll
        for (int k = 0; k < 11; k++) red[wid][k] = acc[k];
    }
    __syncthreads();
    if (threadIdx.x == 0) {
#pragma unroll
        for (int k = 0; k < 11; k++) {
            float s = red[0][k] + red[1][k] + red[2][k] + red[3][k];
            if (k < 10) SD_J[(j * 3 + c) * 10 + k] = s;
            else        Jt[j * 3 + c] = s;
        }
    }
}

// ---------------------------------------------------------------------------
// K2: per-sample joints + rodrigues + FK.  grid = N, block = 64.
__global__ void k2_fk(const float* __restrict__ betas,
                      const float* __restrict__ thetas,
                      const float* __restrict__ SD_J,
                      const float* __restrict__ Jt,
                      float* __restrict__ Gout,
                      float* __restrict__ lrot) {
    int n = blockIdx.x;
    int j = threadIdx.x;

    __shared__ float bsh[10];
    __shared__ float Jl[24][3];
    __shared__ float A[24][12];
    __shared__ float Gs[24][12];

    if (threadIdx.x < 10) bsh[threadIdx.x] = betas[n * 10 + threadIdx.x];
    if (threadIdx.x == 0) lrot[(size_t)n * 208 + 207] = 0.f;
    __syncthreads();

    if (j < 24) {
#pragma unroll
        for (int c = 0; c < 3; c++) {
            float s = Jt[j * 3 + c];
            const float* sp = SD_J + (j * 3 + c) * 10;
#pragma unroll
            for (int k = 0; k < 10; k++) s += bsh[k] * sp[k];
            Jl[j][c] = s;
        }
    }
    __syncthreads();

    if (j < 24) {
        float rx = thetas[n * 72 + j * 3 + 0];
        float ry = thetas[n * 72 + j * 3 + 1];
        float rz = thetas[n * 72 + j * 3 + 2];
        float th = sqrtf(rx * rx + ry * ry + rz * rz) + 1e-8f;
        float inv = 1.f / th;
        float hx = rx * inv, hy = ry * inv, hz = rz * inv;
        float ct = cosf(th), st = sinf(th), omc = 1.f - ct;
        float R[3][3];
        R[0][0] = ct + omc * hx * hx;
        R[0][1] = omc * hx * hy - st * hz;
        R[0][2] = omc * hx * hz + st * hy;
        R[1][0] = omc * hx * hy + st * hz;
        R[1][1] = ct + omc * hy * hy;
        R[1][2] = omc * hy * hz - st * hx;
        R[2][0] = omc * hx * hz - st * hy;
        R[2][1] = omc * hy * hz + st * hx;
        R[2][2] = ct + omc * hz * hz;

        if (j >= 1) {
            float* lp = lrot + (size_t)n * 208 + (j - 1) * 9;
#pragma unroll
            for (int r = 0; r < 3; r++)
#pragma unroll
                for (int c = 0; c < 3; c++)
                    lp[r * 3 + c] = R[r][c] - ((r == c) ? 1.f : 0.f);
        }
        float tx, ty, tz;
        if (j == 0) { tx = Jl[0][0]; ty = Jl[0][1]; tz = Jl[0][2]; }
        else {
            int p = c_par[j];
            tx = Jl[j][0] - Jl[p][0];
            ty = Jl[j][1] - Jl[p][1];
            tz = Jl[j][2] - Jl[p][2];
        }
#pragma unroll
        for (int r = 0; r < 3; r++) {
            A[j][r * 4 + 0] = R[r][0];
            A[j][r * 4 + 1] = R[r][1];
            A[j][r * 4 + 2] = R[r][2];
        }
        A[j][3] = tx; A[j][7] = ty; A[j][11] = tz;
    }
    __syncthreads();

    if (threadIdx.x == 0) {
#pragma unroll
        for (int q = 0; q < 12; q++) Gs[0][q] = A[0][q];
        for (int i = 1; i < 24; i++) {
            int p = c_par[i];
#pragma unroll
            for (int r = 0; r < 3; r++) {
                float g0 = Gs[p][r * 4 + 0], g1 = Gs[p][r * 4 + 1];
                float g2 = Gs[p][r * 4 + 2], g3 = Gs[p][r * 4 + 3];
#pragma unroll
                for (int c = 0; c < 4; c++) {
                    float s = g0 * A[i][0 * 4 + c] + g1 * A[i][1 * 4 + c] +
                              g2 * A[i][2 * 4 + c];
                    if (c == 3) s += g3;
                    Gs[i][r * 4 + c] = s;
                }
            }
        }
    }
    __syncthreads();

    if (j < 24) {
        float jx = Jl[j][0], jy = Jl[j][1], jz = Jl[j][2];
        float* gp = Gout + (size_t)n * 288 + j * 12;
#pragma unroll
        for (int r = 0; r < 3; r++) {
            float r0 = Gs[j][r * 4 + 0], r1 = Gs[j][r * 4 + 1];
            float r2 = Gs[j][r * 4 + 2], t = Gs[j][r * 4 + 3];
            gp[r * 4 + 0] = r0;
            gp[r * 4 + 1] = r1;
            gp[r * 4 + 2] = r2;
            gp[r * 4 + 3] = t - (r0 * jx + r1 * jy + r2 * jz);
        }
    }
}

// ---------------------------------------------------------------------------
// K2b: pack A_bf [512][224] bf16 feature rows: [betas(10) | 1 | lrot(207) | 0...].
__global__ void k2b_packA(const float* __restrict__ betas,
                          const float* __restrict__ lrot,
                          unsigned short* __restrict__ A_bf) {
    int n = blockIdx.x;
    for (int k = threadIdx.x; k < KDIM; k += 64) {
        float val;
        if (k < 10)       val = betas[n * 10 + k];
        else if (k == 10) val = 1.f;
        else if (k < 218) val = lrot[(size_t)n * 208 + (k - 11)];
        else              val = 0.f;
        A_bf[(size_t)n * KDIM + k] = f2b(val);
    }
}

// ---------------------------------------------------------------------------
// K3G: MFMA GEMM  v_posed[m=512][n'=20736] = A[512][224] x B[224][20736].
// block = 4 waves, each wave owns m-tile m0 = blockIdx.y*64 + wave*16,
// iterates 12 n-tiles.  A-frags register-resident across all K.
// C layout (verified m89/m91): col = lane&15 (n), row = (lane>>4)*4 + reg (m).
__global__ void __launch_bounds__(256)
k3g(const unsigned short* __restrict__ A_bf,
    const unsigned short* __restrict__ B2,
    unsigned short* __restrict__ vposed) {
    const int wave = threadIdx.x >> 6, lane = threadIdx.x & 63;
    const int ln = lane & 15, q = lane >> 4;
    const int m0 = blockIdx.y * 64 + wave * 16;
    const int nt0 = blockIdx.x * 12;

    short8 a[7];
    {
        const int row = m0 + ln;
#pragma unroll
        for (int kc = 0; kc < 7; kc++)
            a[kc] = *(const short8*)(A_bf + (size_t)row * KDIM + kc * 32 + q * 8);
    }
    for (int t = 0; t < 12; t++) {
        const int nt = nt0 + t;
        float4v acc = {0.f, 0.f, 0.f, 0.f};
#pragma unroll
        for (int kc = 0; kc < 7; kc++) {
            short8 b = *(const short8*)(B2 +
                (((size_t)kc * NT + nt) * 16 + ln) * 32 + q * 8);
            acc = __builtin_amdgcn_mfma_f32_16x16x32_bf16(a[kc], b, acc, 0, 0, 0);
        }
        const int np = nt * 16 + ln;
#pragma unroll
        for (int r = 0; r < 4; r++) {
            int m = m0 + q * 4 + r;
            vposed[(size_t)m * NPRIME + np] = f2b(acc[r]);
        }
    }
}

// ---------------------------------------------------------------------------
// K3L: LBS only.  block = 4 waves x (64 lanes x 4 verts); wave w -> samples
// s0 = w*4..w*4+3.  grid = (N/16, NVP/256 = 27).  Reads v_posed coalesced.
__global__ void __launch_bounds__(256)
k3l(const float* __restrict__ trans,
    const unsigned short* __restrict__ vposed,
    const float* __restrict__ w_t,
    const float* __restrict__ G_ws,
    float* __restrict__ out) {
    __shared__ float Lg[16][288];
    __shared__ float Ltr[16][3];

    const int tid = threadIdx.x;
    const int nbase = blockIdx.x * 16;
    const int vbase = blockIdx.y * 256;

    for (int idx = tid; idx < 16 * 288; idx += 256) {
        int s = idx / 288, qq = idx % 288;
        Lg[s][qq] = G_ws[(size_t)(nbase + s) * 288 + qq];
    }
    if (tid < 48) Ltr[tid / 3][tid % 3] = trans[(nbase + tid / 3) * 3 + tid % 3];
    __syncthreads();

    const int lane = tid & 63;
    const int s0 = (tid >> 6) * 4;
    const int v4 = vbase + lane * 4;

    // load v_posed bf16x4 per (sample, coord)
    float vp[4][3][4];
#pragma unroll
    for (int s = 0; s < 4; s++) {
        int n = nbase + s0 + s;
#pragma unroll
        for (int c = 0; c < 3; c++) {
            uint2 u = *(const uint2*)(vposed + (size_t)n * NPRIME + c * NVP + v4);
            vp[s][c][0] = b2f((unsigned short)(u.x & 0xFFFF));
            vp[s][c][1] = b2f((unsigned short)(u.x >> 16));
            vp[s][c][2] = b2f((unsigned short)(u.y & 0xFFFF));
            vp[s][c][3] = b2f((unsigned short)(u.y >> 16));
        }
    }

    float o[4][3][4];
#pragma unroll
    for (int s = 0; s < 4; s++)
#pragma unroll
        for (int c = 0; c < 3; c++)
#pragma unroll
            for (int i = 0; i < 4; i++) o[s][c][i] = 0.f;

    for (int j = 0; j < NJ; j++) {
        float4 w4 = *(const float4*)(w_t + (size_t)j * NVP + v4);
        float wv[4] = {w4.x, w4.y, w4.z, w4.w};
#pragma unroll
        for (int s = 0; s < 4; s++) {
            const float4* g4 = (const float4*)&Lg[s0 + s][j * 12];
            float4 g0 = g4[0], g1 = g4[1], g2 = g4[2];
#pragma unroll
            for (int i = 0; i < 4; i++) {
                float x = vp[s][0][i], y = vp[s][1][i], z = vp[s][2][i];
                float r0 = g0.x * x + g0.y * y + g0.z * z + g0.w;
                float r1 = g1.x * x + g1.y * y + g1.z * z + g1.w;
                float r2 = g2.x * x + g2.y * y + g2.z * z + g2.w;
                o[s][0][i] += wv[i] * r0;
                o[s][1][i] += wv[i] * r1;
                o[s][2][i] += wv[i] * r2;
            }
        }
    }
#pragma unroll
    for (int s = 0; s < 4; s++) {
        int n = nbase + s0 + s;
        float t0 = Ltr[s0 + s][0], t1 = Ltr[s0 + s][1], t2 = Ltr[s0 + s][2];
        float* op = out + ((size_t)n * NV + v4) * 3;
#pragma unroll
        for (int i = 0; i < 4; i++) {
            if (v4 + i < NV) {
                op[i * 3 + 0] = o[s][0][i] + t0;
                op[i * 3 + 1] = o[s][1][i] + t1;
                op[i * 3 + 2] = o[s][2][i] + t2;
            }
        }
    }
}

// ---------------------------------------------------------------------------
// K4: joints[n][j][c] = sum_v result[n][v][c] * jr_t[j][v].  grid = N.
__global__ void k4_joints_t(const float* __restrict__ result,
                            const float* __restrict__ jr_t,
                            float* __restrict__ outj) {
    int n = blockIdx.x;
    int tid = threadIdx.x;
    float acc[72];
#pragma unroll
    for (int q = 0; q < 72; q++) acc[q] = 0.f;

    for (int v = tid; v < NV; v += 256) {
        const float* rp = result + ((size_t)n * NV + v) * 3;
        float r0 = rp[0], r1 = rp[1], r2 = rp[2];
#pragma unroll
        for (int j = 0; j < 24; j++) {
            float wv = jr_t[(size_t)j * NVP + v];
            acc[j * 3 + 0] += wv * r0;
            acc[j * 3 + 1] += wv * r1;
            acc[j * 3 + 2] += wv * r2;
        }
    }
#pragma unroll
    for (int q = 0; q < 72; q++) {
        float x = acc[q];
        for (int off = 32; off > 0; off >>= 1) x += __shfl_down(x, off);
        acc[q] = x;
    }
    __shared__ float red[4][72];
    int lane = tid & 63, wid = tid >> 6;
    if (lane == 0) {
#pragma unroll
        for (int q = 0; q < 72; q++) red[wid][q] = acc[q];
    }
    __syncthreads();
    if (tid < 72) {
        float s = red[0][tid] + red[1][tid] + red[2][tid] + red[3][tid];
        outj[(size_t)n * 72 + tid] = s;
    }
}

// ---------------------------------------------------------------------------
extern "C" void kernel_launch(void* const* d_in, const int* in_sizes, int n_in,
                              void* d_out, int out_size, void* d_ws, size_t ws_size,
                              hipStream_t stream) {
    const float* betas     = (const float*)d_in[0];
    const float* thetas    = (const float*)d_in[1];
    const float* trans     = (const float*)d_in[2];
    const float* v_templ   = (const float*)d_in[3];
    const float* shapedirs = (const float*)d_in[4];
    const float* posedirs  = (const float*)d_in[5];
    const float* Jreg      = (const float*)d_in[6];
    const float* jointreg  = (const float*)d_in[7];
    const float* weights   = (const float*)d_in[8];

    float* out = (float*)d_out;       // fp32: result [N,V,3] then joints [N,24,3]
    const int N = in_sizes[0] / 10;   // 512

    // ws layout (float offsets; bf16 arrays start at 16B-aligned boundaries)
    float* ws    = (float*)d_ws;
    float* SD_J  = ws;                                   // 720
    float* Jt    = ws + 720;                             // 72 (+pad) -> 800
    float* G_ws  = ws + 800;                             // N*288
    float* lrot  = G_ws + (size_t)N * 288;               // N*208
    float* w_t   = lrot + (size_t)N * 208;               // 24*NVP
    float* jr_t  = w_t + 24 * NVP;                       // 24*NVP
    float* sd_t  = jr_t + 24 * NVP;                      // 30*NVP
    float* vt_t  = sd_t + 30 * NVP;                      // 3*NVP
    unsigned short* A_bf = (unsigned short*)(vt_t + 3 * NVP);       // 512*224
    unsigned short* B2   = A_bf + (size_t)512 * KDIM;               // 7*NT*512
    unsigned short* vpos = B2 + (size_t)7 * NT * 512;               // 512*NPRIME

    const int B2_N = 7 * NT * 16 * 32;
    int t_total = B2_N + (24 + 24 + 30 + 3) * NVP;
    t_pack<<<(t_total + 255) / 256, 256, 0, stream>>>(
        posedirs, weights, jointreg, shapedirs, v_templ,
        B2, w_t, jr_t, sd_t, vt_t);

    k1_regress<<<72, 256, 0, stream>>>(Jreg, sd_t, vt_t, SD_J, Jt);
    k2_fk<<<N, 64, 0, stream>>>(betas, thetas, SD_J, Jt, G_ws, lrot);
    k2b_packA<<<N, 64, 0, stream>>>(betas, lrot, A_bf);

    dim3 gg(NT / 12, N / 64);     // (108, 8)
    k3g<<<gg, 256, 0, stream>>>(A_bf, B2, vpos);

    dim3 gl(N / 16, NVP / 256);   // (32, 27)
    k3l<<<gl, 256, 0, stream>>>(trans, vpos, w_t, G_ws, out);

    float* outj = out + (size_t)N * NV * 3;
    k4_joints_t<<<N, 256, 0, stream>>>(out, jr_t, outj);
}

// Round 2
// 231.450 us; speedup vs baseline: 1.0833x; 1.0833x over previous
//
#include <hip/hip_runtime.h>
#include <hip/hip_bf16.h>
#include <math.h>

#define NJ 24
#define NV 6890
#define NVP 6912          // padded vertex count (27*256)
#define NPRIME 20736      // 3*NVP, GEMM N dimension
#define NT 1296           // NPRIME/16 n-tiles
#define KDIM 224          // padded K: [0..9]=betas/sd, [10]=1/vt, [11..217]=lrot/pd, rest 0

__constant__ int c_par[24] = {0, 0, 0, 0, 1, 2, 3, 4, 5, 6, 7, 8, 9, 9, 9,
                              12, 13, 14, 16, 17, 18, 19, 20, 21};

typedef __attribute__((ext_vector_type(8))) short short8;
typedef __attribute__((ext_vector_type(4))) float float4v;

__device__ __forceinline__ unsigned short f2b(float x) {
    __hip_bfloat16 h = __float2bfloat16(x);
    return *reinterpret_cast<unsigned short*>(&h);
}
__device__ __forceinline__ float b2f(unsigned short u) {
    unsigned int w = ((unsigned int)u) << 16;
    return __uint_as_float(w);
}

// ---------------------------------------------------------------------------
// T: pack kernel.
//  B2  : MFMA-tiled bf16 B''[kc][nt][ln16][kk32]; element (k, n'=c*NVP+v):
//        k<10 -> sd[v][c][k]; k==10 -> vt[v][c]; 11<=k<218 -> pd[v][c][k-11]; else 0.
//        Consecutive elements <-> consecutive p: reads AND writes coalesced.
//  w_t / jr_t : f32 [24][NVP];  sd_t: f32 [30][NVP]; vt_t: f32 [3][NVP]
__global__ void t_pack(const float* __restrict__ pd,
                       const float* __restrict__ W,
                       const float* __restrict__ jr,
                       const float* __restrict__ sd,
                       const float* __restrict__ vt,
                       unsigned short* __restrict__ B2,
                       float* __restrict__ w_t,
                       float* __restrict__ jr_t,
                       float* __restrict__ sd_t,
                       float* __restrict__ vt_t) {
    int idx = blockIdx.x * 256 + threadIdx.x;
    const int B2_N = 7 * NT * 16 * 32;        // 4,644,864
    if (idx < B2_N) {
        int kk = idx & 31;
        int ln = (idx >> 5) & 15;
        int rest = idx >> 9;                  // nt + NT*kc
        int nt = rest % NT, kc = rest / NT;
        int k = kc * 32 + kk;
        int np = nt * 16 + ln;
        int c = np / NVP, v = np - c * NVP;
        float val = 0.f;
        if (v < NV) {
            if (k < 10)       val = sd[(size_t)v * 30 + c * 10 + k];
            else if (k == 10) val = vt[v * 3 + c];
            else if (k < 218) val = pd[(size_t)v * 621 + c * 207 + (k - 11)];
        }
        B2[idx] = f2b(val);
        return;
    }
    idx -= B2_N;
    if (idx < 24 * NVP) {
        int j = idx / NVP, v = idx % NVP;
        if (v < NV) w_t[(size_t)j * NVP + v] = W[(size_t)v * 24 + j];
        return;
    }
    idx -= 24 * NVP;
    if (idx < 24 * NVP) {
        int j = idx / NVP, v = idx % NVP;
        if (v < NV) jr_t[(size_t)j * NVP + v] = jr[(size_t)v * 24 + j];
        return;
    }
    idx -= 24 * NVP;
    if (idx < 30 * NVP) {
        int r = idx / NVP, v = idx % NVP;
        if (v < NV) sd_t[(size_t)r * NVP + v] = sd[(size_t)v * 30 + r];
        return;
    }
    idx -= 30 * NVP;
    if (idx < 3 * NVP) {
        int c = idx / NVP, v = idx % NVP;
        if (v < NV) vt_t[(size_t)c * NVP + v] = vt[(size_t)v * 3 + c];
    }
}

// ---------------------------------------------------------------------------
// K1: fold J_regressor into shapedirs / v_template (coalesced, fp32).
__global__ void k1_regress(const float* __restrict__ Jreg,
                           const float* __restrict__ sd_t,
                           const float* __restrict__ vt_t,
                           float* __restrict__ SD_J,
                           float* __restrict__ Jt) {
    int j = blockIdx.x / 3;
    int c = blockIdx.x % 3;
    float acc[11];
#pragma unroll
    for (int k = 0; k < 11; k++) acc[k] = 0.f;

    for (int v = threadIdx.x; v < NV; v += 256) {
        float r = Jreg[j * NV + v];
#pragma unroll
        for (int k = 0; k < 10; k++)
            acc[k] += r * sd_t[(size_t)(c * 10 + k) * NVP + v];
        acc[10] += r * vt_t[(size_t)c * NVP + v];
    }
#pragma unroll
    for (int k = 0; k < 11; k++) {
        float x = acc[k];
        for (int off = 32; off > 0; off >>= 1) x += __shfl_down(x, off);
        acc[k] = x;
    }
    __shared__ float red[4][11];
    int lane = threadIdx.x & 63, wid = threadIdx.x >> 6;
    if (lane == 0) {
#pragma unroll
        for (int k = 0; k < 11; k++) red[wid][k] = acc[k];
    }
    __syncthreads();
    if (threadIdx.x == 0) {
#pragma unroll
        for (int k = 0; k < 11; k++) {
            float s = red[0][k] + red[1][k] + red[2][k] + red[3][k];
            if (k < 10) SD_J[(j * 3 + c) * 10 + k] = s;
            else        Jt[j * 3 + c] = s;
        }
    }
}

// ---------------------------------------------------------------------------
// K2: per-sample joints + rodrigues + FK.  grid = N, block = 64.
__global__ void k2_fk(const float* __restrict__ betas,
                      const float* __restrict__ thetas,
                      const float* __restrict__ SD_J,
                      const float* __restrict__ Jt,
                      float* __restrict__ Gout,
                      float* __restrict__ lrot) {
    int n = blockIdx.x;
    int j = threadIdx.x;

    __shared__ float bsh[10];
    __shared__ float Jl[24][3];
    __shared__ float A[24][12];
    __shared__ float Gs[24][12];

    if (threadIdx.x < 10) bsh[threadIdx.x] = betas[n * 10 + threadIdx.x];
    if (threadIdx.x == 0) lrot[(size_t)n * 208 + 207] = 0.f;
    __syncthreads();

    if (j < 24) {
#pragma unroll
        for (int c = 0; c < 3; c++) {
            float s = Jt[j * 3 + c];
            const float* sp = SD_J + (j * 3 + c) * 10;
#pragma unroll
            for (int k = 0; k < 10; k++) s += bsh[k] * sp[k];
            Jl[j][c] = s;
        }
    }
    __syncthreads();

    if (j < 24) {
        float rx = thetas[n * 72 + j * 3 + 0];
        float ry = thetas[n * 72 + j * 3 + 1];
        float rz = thetas[n * 72 + j * 3 + 2];
        float th = sqrtf(rx * rx + ry * ry + rz * rz) + 1e-8f;
        float inv = 1.f / th;
        float hx = rx * inv, hy = ry * inv, hz = rz * inv;
        float ct = cosf(th), st = sinf(th), omc = 1.f - ct;
        float R[3][3];
        R[0][0] = ct + omc * hx * hx;
        R[0][1] = omc * hx * hy - st * hz;
        R[0][2] = omc * hx * hz + st * hy;
        R[1][0] = omc * hx * hy + st * hz;
        R[1][1] = ct + omc * hy * hy;
        R[1][2] = omc * hy * hz - st * hx;
        R[2][0] = omc * hx * hz - st * hy;
        R[2][1] = omc * hy * hz + st * hx;
        R[2][2] = ct + omc * hz * hz;

        if (j >= 1) {
            float* lp = lrot + (size_t)n * 208 + (j - 1) * 9;
#pragma unroll
            for (int r = 0; r < 3; r++)
#pragma unroll
                for (int c = 0; c < 3; c++)
                    lp[r * 3 + c] = R[r][c] - ((r == c) ? 1.f : 0.f);
        }
        float tx, ty, tz;
        if (j == 0) { tx = Jl[0][0]; ty = Jl[0][1]; tz = Jl[0][2]; }
        else {
            int p = c_par[j];
            tx = Jl[j][0] - Jl[p][0];
            ty = Jl[j][1] - Jl[p][1];
            tz = Jl[j][2] - Jl[p][2];
        }
#pragma unroll
        for (int r = 0; r < 3; r++) {
            A[j][r * 4 + 0] = R[r][0];
            A[j][r * 4 + 1] = R[r][1];
            A[j][r * 4 + 2] = R[r][2];
        }
        A[j][3] = tx; A[j][7] = ty; A[j][11] = tz;
    }
    __syncthreads();

    if (threadIdx.x == 0) {
#pragma unroll
        for (int q = 0; q < 12; q++) Gs[0][q] = A[0][q];
        for (int i = 1; i < 24; i++) {
            int p = c_par[i];
#pragma unroll
            for (int r = 0; r < 3; r++) {
                float g0 = Gs[p][r * 4 + 0], g1 = Gs[p][r * 4 + 1];
                float g2 = Gs[p][r * 4 + 2], g3 = Gs[p][r * 4 + 3];
#pragma unroll
                for (int c = 0; c < 4; c++) {
                    float s = g0 * A[i][0 * 4 + c] + g1 * A[i][1 * 4 + c] +
                              g2 * A[i][2 * 4 + c];
                    if (c == 3) s += g3;
                    Gs[i][r * 4 + c] = s;
                }
            }
        }
    }
    __syncthreads();

    if (j < 24) {
        float jx = Jl[j][0], jy = Jl[j][1], jz = Jl[j][2];
        float* gp = Gout + (size_t)n * 288 + j * 12;
#pragma unroll
        for (int r = 0; r < 3; r++) {
            float r0 = Gs[j][r * 4 + 0], r1 = Gs[j][r * 4 + 1];
            float r2 = Gs[j][r * 4 + 2], t = Gs[j][r * 4 + 3];
            gp[r * 4 + 0] = r0;
            gp[r * 4 + 1] = r1;
            gp[r * 4 + 2] = r2;
            gp[r * 4 + 3] = t - (r0 * jx + r1 * jy + r2 * jz);
        }
    }
}

// ---------------------------------------------------------------------------
// K2b: pack A_bf [512][224] bf16 feature rows: [betas(10) | 1 | lrot(207) | 0...].
__global__ void k2b_packA(const float* __restrict__ betas,
                          const float* __restrict__ lrot,
                          unsigned short* __restrict__ A_bf) {
    int n = blockIdx.x;
    for (int k = threadIdx.x; k < KDIM; k += 64) {
        float val;
        if (k < 10)       val = betas[n * 10 + k];
        else if (k == 10) val = 1.f;
        else if (k < 218) val = lrot[(size_t)n * 208 + (k - 11)];
        else              val = 0.f;
        A_bf[(size_t)n * KDIM + k] = f2b(val);
    }
}

// ---------------------------------------------------------------------------
// K3G: MFMA GEMM  v_posed[m=512][n'=20736] = A[512][224] x B[224][20736].
// block = 4 waves, each wave owns m-tile m0 = blockIdx.y*64 + wave*16,
// iterates 12 n-tiles.  A-frags register-resident across all K.
// C layout (verified m89/m91): col = lane&15 (n), row = (lane>>4)*4 + reg (m).
__global__ void __launch_bounds__(256)
k3g(const unsigned short* __restrict__ A_bf,
    const unsigned short* __restrict__ B2,
    unsigned short* __restrict__ vposed) {
    const int wave = threadIdx.x >> 6, lane = threadIdx.x & 63;
    const int ln = lane & 15, q = lane >> 4;
    const int m0 = blockIdx.y * 64 + wave * 16;
    const int nt0 = blockIdx.x * 12;

    short8 a[7];
    {
        const int row = m0 + ln;
#pragma unroll
        for (int kc = 0; kc < 7; kc++)
            a[kc] = *(const short8*)(A_bf + (size_t)row * KDIM + kc * 32 + q * 8);
    }
    for (int t = 0; t < 12; t++) {
        const int nt = nt0 + t;
        float4v acc = {0.f, 0.f, 0.f, 0.f};
#pragma unroll
        for (int kc = 0; kc < 7; kc++) {
            short8 b = *(const short8*)(B2 +
                (((size_t)kc * NT + nt) * 16 + ln) * 32 + q * 8);
            acc = __builtin_amdgcn_mfma_f32_16x16x32_bf16(a[kc], b, acc, 0, 0, 0);
        }
        const int np = nt * 16 + ln;
#pragma unroll
        for (int r = 0; r < 4; r++) {
            int m = m0 + q * 4 + r;
            vposed[(size_t)m * NPRIME + np] = f2b(acc[r]);
        }
    }
}

// ---------------------------------------------------------------------------
// K3L: LBS only.  RESTRUCTURED for occupancy (was 15% occ, 34% VALUBusy,
// 864 blocks, 116 VGPR): now 1 sample per WAVE, 4 verts per lane.
// block = 4 waves = 4 samples x 256 verts; grid = (N/4, NVP/256) = (128, 27)
// = 3456 blocks (13.5/CU).  Per-thread state: vp[3][4] + o[3][4] -> low VGPR,
// target 6-8 waves/SIMD resident.
__global__ void __launch_bounds__(256)
k3l(const float* __restrict__ trans,
    const unsigned short* __restrict__ vposed,
    const float* __restrict__ w_t,
    const float* __restrict__ G_ws,
    float* __restrict__ out) {
    __shared__ float Lg[4][288];
    __shared__ float Ltr[4][3];

    const int tid = threadIdx.x;
    const int nbase = blockIdx.x * 4;
    const int vbase = blockIdx.y * 256;

    for (int idx = tid; idx < 4 * 288; idx += 256) {
        int s = idx >> 8 /*unused*/, qq;
        // simple 2D decode: idx = s*288 + qq
        s = idx / 288; qq = idx - s * 288;
        Lg[s][qq] = G_ws[(size_t)(nbase + s) * 288 + qq];
    }
    if (tid < 12) Ltr[tid / 3][tid % 3] = trans[(nbase + tid / 3) * 3 + tid % 3];
    __syncthreads();

    const int lane = tid & 63;
    const int s = tid >> 6;               // wave id == sample offset
    const int n = nbase + s;
    const int v4 = vbase + lane * 4;

    // load v_posed bf16x4 per coord (coalesced: 8B/lane)
    float vp[3][4];
#pragma unroll
    for (int c = 0; c < 3; c++) {
        uint2 u = *(const uint2*)(vposed + (size_t)n * NPRIME + c * NVP + v4);
        vp[c][0] = b2f((unsigned short)(u.x & 0xFFFF));
        vp[c][1] = b2f((unsigned short)(u.x >> 16));
        vp[c][2] = b2f((unsigned short)(u.y & 0xFFFF));
        vp[c][3] = b2f((unsigned short)(u.y >> 16));
    }

    float o[3][4];
#pragma unroll
    for (int c = 0; c < 3; c++)
#pragma unroll
        for (int i = 0; i < 4; i++) o[c][i] = 0.f;

    for (int j = 0; j < NJ; j++) {
        float4 w4 = *(const float4*)(w_t + (size_t)j * NVP + v4);
        float wv[4] = {w4.x, w4.y, w4.z, w4.w};
        const float4* g4 = (const float4*)&Lg[s][j * 12];   // broadcast reads
        float4 g0 = g4[0], g1 = g4[1], g2 = g4[2];
#pragma unroll
        for (int i = 0; i < 4; i++) {
            float x = vp[0][i], y = vp[1][i], z = vp[2][i];
            float r0 = g0.x * x + g0.y * y + g0.z * z + g0.w;
            float r1 = g1.x * x + g1.y * y + g1.z * z + g1.w;
            float r2 = g2.x * x + g2.y * y + g2.z * z + g2.w;
            o[0][i] += wv[i] * r0;
            o[1][i] += wv[i] * r1;
            o[2][i] += wv[i] * r2;
        }
    }

    {
        float t0 = Ltr[s][0], t1 = Ltr[s][1], t2 = Ltr[s][2];
        float* op = out + ((size_t)n * NV + v4) * 3;
#pragma unroll
        for (int i = 0; i < 4; i++) {
            if (v4 + i < NV) {
                op[i * 3 + 0] = o[0][i] + t0;
                op[i * 3 + 1] = o[1][i] + t1;
                op[i * 3 + 2] = o[2][i] + t2;
            }
        }
    }
}

// ---------------------------------------------------------------------------
// K4: joints[n][j][c] = sum_v result[n][v][c] * jr_t[j][v].  grid = N.
__global__ void k4_joints_t(const float* __restrict__ result,
                            const float* __restrict__ jr_t,
                            float* __restrict__ outj) {
    int n = blockIdx.x;
    int tid = threadIdx.x;
    float acc[72];
#pragma unroll
    for (int q = 0; q < 72; q++) acc[q] = 0.f;

    for (int v = tid; v < NV; v += 256) {
        const float* rp = result + ((size_t)n * NV + v) * 3;
        float r0 = rp[0], r1 = rp[1], r2 = rp[2];
#pragma unroll
        for (int j = 0; j < 24; j++) {
            float wv = jr_t[(size_t)j * NVP + v];
            acc[j * 3 + 0] += wv * r0;
            acc[j * 3 + 1] += wv * r1;
            acc[j * 3 + 2] += wv * r2;
        }
    }
#pragma unroll
    for (int q = 0; q < 72; q++) {
        float x = acc[q];
        for (int off = 32; off > 0; off >>= 1) x += __shfl_down(x, off);
        acc[q] = x;
    }
    __shared__ float red[4][72];
    int lane = tid & 63, wid = tid >> 6;
    if (lane == 0) {
#pragma unroll
        for (int q = 0; q < 72; q++) red[wid][q] = acc[q];
    }
    __syncthreads();
    if (tid < 72) {
        float s = red[0][tid] + red[1][tid] + red[2][tid] + red[3][tid];
        outj[(size_t)n * 72 + tid] = s;
    }
}

// ---------------------------------------------------------------------------
extern "C" void kernel_launch(void* const* d_in, const int* in_sizes, int n_in,
                              void* d_out, int out_size, void* d_ws, size_t ws_size,
                              hipStream_t stream) {
    const float* betas     = (const float*)d_in[0];
    const float* thetas    = (const float*)d_in[1];
    const float* trans     = (const float*)d_in[2];
    const float* v_templ   = (const float*)d_in[3];
    const float* shapedirs = (const float*)d_in[4];
    const float* posedirs  = (const float*)d_in[5];
    const float* Jreg      = (const float*)d_in[6];
    const float* jointreg  = (const float*)d_in[7];
    const float* weights   = (const float*)d_in[8];

    float* out = (float*)d_out;       // fp32: result [N,V,3] then joints [N,24,3]
    const int N = in_sizes[0] / 10;   // 512

    // ws layout (float offsets; bf16 arrays start at 16B-aligned boundaries)
    float* ws    = (float*)d_ws;
    float* SD_J  = ws;                                   // 720
    float* Jt    = ws + 720;                             // 72 (+pad) -> 800
    float* G_ws  = ws + 800;                             // N*288
    float* lrot  = G_ws + (size_t)N * 288;               // N*208
    float* w_t   = lrot + (size_t)N * 208;               // 24*NVP
    float* jr_t  = w_t + 24 * NVP;                       // 24*NVP
    float* sd_t  = jr_t + 24 * NVP;                      // 30*NVP
    float* vt_t  = sd_t + 30 * NVP;                      // 3*NVP
    unsigned short* A_bf = (unsigned short*)(vt_t + 3 * NVP);       // 512*224
    unsigned short* B2   = A_bf + (size_t)512 * KDIM;               // 7*NT*512
    unsigned short* vpos = B2 + (size_t)7 * NT * 512;               // 512*NPRIME

    const int B2_N = 7 * NT * 16 * 32;
    int t_total = B2_N + (24 + 24 + 30 + 3) * NVP;
    t_pack<<<(t_total + 255) / 256, 256, 0, stream>>>(
        posedirs, weights, jointreg, shapedirs, v_templ,
        B2, w_t, jr_t, sd_t, vt_t);

    k1_regress<<<72, 256, 0, stream>>>(Jreg, sd_t, vt_t, SD_J, Jt);
    k2_fk<<<N, 64, 0, stream>>>(betas, thetas, SD_J, Jt, G_ws, lrot);
    k2b_packA<<<N, 64, 0, stream>>>(betas, lrot, A_bf);

    dim3 gg(NT / 12, N / 64);     // (108, 8)
    k3g<<<gg, 256, 0, stream>>>(A_bf, B2, vpos);

    dim3 gl(N / 4, NVP / 256);    // (128, 27) = 3456 blocks
    k3l<<<gl, 256, 0, stream>>>(trans, vpos, w_t, G_ws, out);

    float* outj = out + (size_t)N * NV * 3;
    k4_joints_t<<<N, 256, 0, stream>>>(out, jr_t, outj);
}

// Round 3
// 231.141 us; speedup vs baseline: 1.0848x; 1.0013x over previous
//
#include <hip/hip_runtime.h>
#include <hip/hip_bf16.h>
#include <math.h>

#define NJ 24
#define NV 6890
#define NVP 6912          // padded vertex count (27*256)
#define NPRIME 20736      // 3*NVP, GEMM N dimension
#define NT 1296           // NPRIME/16 n-tiles
#define KDIM 224          // padded K: [0..9]=betas/sd, [10]=1/vt, [11..217]=lrot/pd, rest 0

__constant__ int c_par[24] = {0, 0, 0, 0, 1, 2, 3, 4, 5, 6, 7, 8, 9, 9, 9,
                              12, 13, 14, 16, 17, 18, 19, 20, 21};

typedef __attribute__((ext_vector_type(8))) short short8;
typedef __attribute__((ext_vector_type(4))) float float4v;

__device__ __forceinline__ unsigned short f2b(float x) {
    __hip_bfloat16 h = __float2bfloat16(x);
    return *reinterpret_cast<unsigned short*>(&h);
}
__device__ __forceinline__ float b2f(unsigned short u) {
    unsigned int w = ((unsigned int)u) << 16;
    return __uint_as_float(w);
}

// ---------------------------------------------------------------------------
// T: pack kernel.  (unchanged)
__global__ void t_pack(const float* __restrict__ pd,
                       const float* __restrict__ W,
                       const float* __restrict__ jr,
                       const float* __restrict__ sd,
                       const float* __restrict__ vt,
                       unsigned short* __restrict__ B2,
                       float* __restrict__ w_t,
                       float* __restrict__ jr_t,
                       float* __restrict__ sd_t,
                       float* __restrict__ vt_t) {
    int idx = blockIdx.x * 256 + threadIdx.x;
    const int B2_N = 7 * NT * 16 * 32;        // 4,644,864
    if (idx < B2_N) {
        int kk = idx & 31;
        int ln = (idx >> 5) & 15;
        int rest = idx >> 9;                  // nt + NT*kc
        int nt = rest % NT, kc = rest / NT;
        int k = kc * 32 + kk;
        int np = nt * 16 + ln;
        int c = np / NVP, v = np - c * NVP;
        float val = 0.f;
        if (v < NV) {
            if (k < 10)       val = sd[(size_t)v * 30 + c * 10 + k];
            else if (k == 10) val = vt[v * 3 + c];
            else if (k < 218) val = pd[(size_t)v * 621 + c * 207 + (k - 11)];
        }
        B2[idx] = f2b(val);
        return;
    }
    idx -= B2_N;
    if (idx < 24 * NVP) {
        int j = idx / NVP, v = idx % NVP;
        if (v < NV) w_t[(size_t)j * NVP + v] = W[(size_t)v * 24 + j];
        return;
    }
    idx -= 24 * NVP;
    if (idx < 24 * NVP) {
        int j = idx / NVP, v = idx % NVP;
        if (v < NV) jr_t[(size_t)j * NVP + v] = jr[(size_t)v * 24 + j];
        return;
    }
    idx -= 24 * NVP;
    if (idx < 30 * NVP) {
        int r = idx / NVP, v = idx % NVP;
        if (v < NV) sd_t[(size_t)r * NVP + v] = sd[(size_t)v * 30 + r];
        return;
    }
    idx -= 30 * NVP;
    if (idx < 3 * NVP) {
        int c = idx / NVP, v = idx % NVP;
        if (v < NV) vt_t[(size_t)c * NVP + v] = vt[(size_t)v * 3 + c];
    }
}

// ---------------------------------------------------------------------------
// K1: fold J_regressor into shapedirs / v_template (coalesced, fp32). (unchanged)
__global__ void k1_regress(const float* __restrict__ Jreg,
                           const float* __restrict__ sd_t,
                           const float* __restrict__ vt_t,
                           float* __restrict__ SD_J,
                           float* __restrict__ Jt) {
    int j = blockIdx.x / 3;
    int c = blockIdx.x % 3;
    float acc[11];
#pragma unroll
    for (int k = 0; k < 11; k++) acc[k] = 0.f;

    for (int v = threadIdx.x; v < NV; v += 256) {
        float r = Jreg[j * NV + v];
#pragma unroll
        for (int k = 0; k < 10; k++)
            acc[k] += r * sd_t[(size_t)(c * 10 + k) * NVP + v];
        acc[10] += r * vt_t[(size_t)c * NVP + v];
    }
#pragma unroll
    for (int k = 0; k < 11; k++) {
        float x = acc[k];
        for (int off = 32; off > 0; off >>= 1) x += __shfl_down(x, off);
        acc[k] = x;
    }
    __shared__ float red[4][11];
    int lane = threadIdx.x & 63, wid = threadIdx.x >> 6;
    if (lane == 0) {
#pragma unroll
        for (int k = 0; k < 11; k++) red[wid][k] = acc[k];
    }
    __syncthreads();
    if (threadIdx.x == 0) {
#pragma unroll
        for (int k = 0; k < 11; k++) {
            float s = red[0][k] + red[1][k] + red[2][k] + red[3][k];
            if (k < 10) SD_J[(j * 3 + c) * 10 + k] = s;
            else        Jt[j * 3 + c] = s;
        }
    }
}

// ---------------------------------------------------------------------------
// K2: per-sample joints + rodrigues + FK + A_bf pack (k2b fused via LDS;
// lrot global round-trip eliminated).  grid = N, block = 64.
__global__ void k2_fk(const float* __restrict__ betas,
                      const float* __restrict__ thetas,
                      const float* __restrict__ SD_J,
                      const float* __restrict__ Jt,
                      float* __restrict__ Gout,
                      unsigned short* __restrict__ A_bf) {
    int n = blockIdx.x;
    int j = threadIdx.x;

    __shared__ float bsh[10];
    __shared__ float Jl[24][3];
    __shared__ float A[24][12];
    __shared__ float Gs[24][12];
    __shared__ float lr[208];     // lrotmin staging for A_bf pack

    if (threadIdx.x < 10) bsh[threadIdx.x] = betas[n * 10 + threadIdx.x];
    if (threadIdx.x == 0) lr[207] = 0.f;
    __syncthreads();

    if (j < 24) {
#pragma unroll
        for (int c = 0; c < 3; c++) {
            float s = Jt[j * 3 + c];
            const float* sp = SD_J + (j * 3 + c) * 10;
#pragma unroll
            for (int k = 0; k < 10; k++) s += bsh[k] * sp[k];
            Jl[j][c] = s;
        }
    }
    __syncthreads();

    if (j < 24) {
        float rx = thetas[n * 72 + j * 3 + 0];
        float ry = thetas[n * 72 + j * 3 + 1];
        float rz = thetas[n * 72 + j * 3 + 2];
        float th = sqrtf(rx * rx + ry * ry + rz * rz) + 1e-8f;
        float inv = 1.f / th;
        float hx = rx * inv, hy = ry * inv, hz = rz * inv;
        float ct = cosf(th), st = sinf(th), omc = 1.f - ct;
        float R[3][3];
        R[0][0] = ct + omc * hx * hx;
        R[0][1] = omc * hx * hy - st * hz;
        R[0][2] = omc * hx * hz + st * hy;
        R[1][0] = omc * hx * hy + st * hz;
        R[1][1] = ct + omc * hy * hy;
        R[1][2] = omc * hy * hz - st * hx;
        R[2][0] = omc * hx * hz - st * hy;
        R[2][1] = omc * hy * hz + st * hx;
        R[2][2] = ct + omc * hz * hz;

        if (j >= 1) {
            float* lp = &lr[(j - 1) * 9];
#pragma unroll
            for (int r = 0; r < 3; r++)
#pragma unroll
                for (int c = 0; c < 3; c++)
                    lp[r * 3 + c] = R[r][c] - ((r == c) ? 1.f : 0.f);
        }
        float tx, ty, tz;
        if (j == 0) { tx = Jl[0][0]; ty = Jl[0][1]; tz = Jl[0][2]; }
        else {
            int p = c_par[j];
            tx = Jl[j][0] - Jl[p][0];
            ty = Jl[j][1] - Jl[p][1];
            tz = Jl[j][2] - Jl[p][2];
        }
#pragma unroll
        for (int r = 0; r < 3; r++) {
            A[j][r * 4 + 0] = R[r][0];
            A[j][r * 4 + 1] = R[r][1];
            A[j][r * 4 + 2] = R[r][2];
        }
        A[j][3] = tx; A[j][7] = ty; A[j][11] = tz;
    }
    __syncthreads();

    // lane 0: serial FK; all lanes: pack A_bf row from LDS (independent work)
    if (threadIdx.x == 0) {
#pragma unroll
        for (int q = 0; q < 12; q++) Gs[0][q] = A[0][q];
        for (int i = 1; i < 24; i++) {
            int p = c_par[i];
#pragma unroll
            for (int r = 0; r < 3; r++) {
                float g0 = Gs[p][r * 4 + 0], g1 = Gs[p][r * 4 + 1];
                float g2 = Gs[p][r * 4 + 2], g3 = Gs[p][r * 4 + 3];
#pragma unroll
                for (int c = 0; c < 4; c++) {
                    float s = g0 * A[i][0 * 4 + c] + g1 * A[i][1 * 4 + c] +
                              g2 * A[i][2 * 4 + c];
                    if (c == 3) s += g3;
                    Gs[i][r * 4 + c] = s;
                }
            }
        }
    }
    for (int k = threadIdx.x; k < KDIM; k += 64) {
        float val;
        if (k < 10)       val = bsh[k];
        else if (k == 10) val = 1.f;
        else if (k < 218) val = lr[k - 11];
        else              val = 0.f;
        A_bf[(size_t)n * KDIM + k] = f2b(val);
    }
    __syncthreads();

    if (j < 24) {
        float jx = Jl[j][0], jy = Jl[j][1], jz = Jl[j][2];
        float* gp = Gout + (size_t)n * 288 + j * 12;
#pragma unroll
        for (int r = 0; r < 3; r++) {
            float r0 = Gs[j][r * 4 + 0], r1 = Gs[j][r * 4 + 1];
            float r2 = Gs[j][r * 4 + 2], t = Gs[j][r * 4 + 3];
            gp[r * 4 + 0] = r0;
            gp[r * 4 + 1] = r1;
            gp[r * 4 + 2] = r2;
            gp[r * 4 + 3] = t - (r0 * jx + r1 * jy + r2 * jz);
        }
    }
}

// ---------------------------------------------------------------------------
// K3G: MFMA GEMM  (unchanged)
__global__ void __launch_bounds__(256)
k3g(const unsigned short* __restrict__ A_bf,
    const unsigned short* __restrict__ B2,
    unsigned short* __restrict__ vposed) {
    const int wave = threadIdx.x >> 6, lane = threadIdx.x & 63;
    const int ln = lane & 15, q = lane >> 4;
    const int m0 = blockIdx.y * 64 + wave * 16;
    const int nt0 = blockIdx.x * 12;

    short8 a[7];
    {
        const int row = m0 + ln;
#pragma unroll
        for (int kc = 0; kc < 7; kc++)
            a[kc] = *(const short8*)(A_bf + (size_t)row * KDIM + kc * 32 + q * 8);
    }
    for (int t = 0; t < 12; t++) {
        const int nt = nt0 + t;
        float4v acc = {0.f, 0.f, 0.f, 0.f};
#pragma unroll
        for (int kc = 0; kc < 7; kc++) {
            short8 b = *(const short8*)(B2 +
                (((size_t)kc * NT + nt) * 16 + ln) * 32 + q * 8);
            acc = __builtin_amdgcn_mfma_f32_16x16x32_bf16(a[kc], b, acc, 0, 0, 0);
        }
        const int np = nt * 16 + ln;
#pragma unroll
        for (int r = 0; r < 4; r++) {
            int m = m0 + q * 4 + r;
            vposed[(size_t)m * NPRIME + np] = f2b(acc[r]);
        }
    }
}

// ---------------------------------------------------------------------------
// K3L: LBS.  (unchanged from round 1: 1 sample/wave, grid (128,27))
__global__ void __launch_bounds__(256)
k3l(const float* __restrict__ trans,
    const unsigned short* __restrict__ vposed,
    const float* __restrict__ w_t,
    const float* __restrict__ G_ws,
    float* __restrict__ out) {
    __shared__ float Lg[4][288];
    __shared__ float Ltr[4][3];

    const int tid = threadIdx.x;
    const int nbase = blockIdx.x * 4;
    const int vbase = blockIdx.y * 256;

    for (int idx = tid; idx < 4 * 288; idx += 256) {
        int s = idx / 288, qq = idx - (idx / 288) * 288;
        Lg[s][qq] = G_ws[(size_t)(nbase + s) * 288 + qq];
    }
    if (tid < 12) Ltr[tid / 3][tid % 3] = trans[(nbase + tid / 3) * 3 + tid % 3];
    __syncthreads();

    const int lane = tid & 63;
    const int s = tid >> 6;               // wave id == sample offset
    const int n = nbase + s;
    const int v4 = vbase + lane * 4;

    float vp[3][4];
#pragma unroll
    for (int c = 0; c < 3; c++) {
        uint2 u = *(const uint2*)(vposed + (size_t)n * NPRIME + c * NVP + v4);
        vp[c][0] = b2f((unsigned short)(u.x & 0xFFFF));
        vp[c][1] = b2f((unsigned short)(u.x >> 16));
        vp[c][2] = b2f((unsigned short)(u.y & 0xFFFF));
        vp[c][3] = b2f((unsigned short)(u.y >> 16));
    }

    float o[3][4];
#pragma unroll
    for (int c = 0; c < 3; c++)
#pragma unroll
        for (int i = 0; i < 4; i++) o[c][i] = 0.f;

    for (int j = 0; j < NJ; j++) {
        float4 w4 = *(const float4*)(w_t + (size_t)j * NVP + v4);
        float wv[4] = {w4.x, w4.y, w4.z, w4.w};
        const float4* g4 = (const float4*)&Lg[s][j * 12];   // broadcast reads
        float4 g0 = g4[0], g1 = g4[1], g2 = g4[2];
#pragma unroll
        for (int i = 0; i < 4; i++) {
            float x = vp[0][i], y = vp[1][i], z = vp[2][i];
            float r0 = g0.x * x + g0.y * y + g0.z * z + g0.w;
            float r1 = g1.x * x + g1.y * y + g1.z * z + g1.w;
            float r2 = g2.x * x + g2.y * y + g2.z * z + g2.w;
            o[0][i] += wv[i] * r0;
            o[1][i] += wv[i] * r1;
            o[2][i] += wv[i] * r2;
        }
    }

    {
        float t0 = Ltr[s][0], t1 = Ltr[s][1], t2 = Ltr[s][2];
        float* op = out + ((size_t)n * NV + v4) * 3;
#pragma unroll
        for (int i = 0; i < 4; i++) {
            if (v4 + i < NV) {
                op[i * 3 + 0] = o[0][i] + t0;
                op[i * 3 + 1] = o[1][i] + t1;
                op[i * 3 + 2] = o[2][i] + t2;
            }
        }
    }
}

// ---------------------------------------------------------------------------
// K4: joints[n][j][c] = sum_v result[n][v][c] * jr_t[j][v].  grid = N.
// REWRITTEN: old version held acc[72]/thread -> scratch spill (VGPR capped 64,
// WRITE_SIZE 15.5 MB of spill traffic, VALUBusy 0.7%).  Now each of the 4
// waves owns 6 joints x 3 coords = 18 accumulators (~30 VGPR, no spill);
// each wave strides all verts.  result[n] (83 KB) is L2-resident for the
// 4x wave re-read.
__global__ void __launch_bounds__(256)
k4_joints_t(const float* __restrict__ result,
            const float* __restrict__ jr_t,
            float* __restrict__ outj) {
    const int n = blockIdx.x;
    const int wid = threadIdx.x >> 6, lane = threadIdx.x & 63;
    const int j0 = wid * 6;

    float acc[18];
#pragma unroll
    for (int q = 0; q < 18; q++) acc[q] = 0.f;

    const float* rb = result + (size_t)n * NV * 3;
    for (int v = lane; v < NV; v += 64) {
        float r0 = rb[v * 3 + 0], r1 = rb[v * 3 + 1], r2 = rb[v * 3 + 2];
#pragma unroll
        for (int jj = 0; jj < 6; jj++) {
            float w = jr_t[(size_t)(j0 + jj) * NVP + v];
            acc[jj * 3 + 0] += w * r0;
            acc[jj * 3 + 1] += w * r1;
            acc[jj * 3 + 2] += w * r2;
        }
    }
#pragma unroll
    for (int q = 0; q < 18; q++) {
        float x = acc[q];
        for (int off = 32; off > 0; off >>= 1) x += __shfl_down(x, off);
        acc[q] = x;
    }
    if (lane == 0) {
#pragma unroll
        for (int q = 0; q < 18; q++)
            outj[(size_t)n * 72 + wid * 18 + q] = acc[q];
    }
}

// ---------------------------------------------------------------------------
extern "C" void kernel_launch(void* const* d_in, const int* in_sizes, int n_in,
                              void* d_out, int out_size, void* d_ws, size_t ws_size,
                              hipStream_t stream) {
    const float* betas     = (const float*)d_in[0];
    const float* thetas    = (const float*)d_in[1];
    const float* trans     = (const float*)d_in[2];
    const float* v_templ   = (const float*)d_in[3];
    const float* shapedirs = (const float*)d_in[4];
    const float* posedirs  = (const float*)d_in[5];
    const float* Jreg      = (const float*)d_in[6];
    const float* jointreg  = (const float*)d_in[7];
    const float* weights   = (const float*)d_in[8];

    float* out = (float*)d_out;       // fp32: result [N,V,3] then joints [N,24,3]
    const int N = in_sizes[0] / 10;   // 512

    // ws layout (float offsets; bf16 arrays start at 16B-aligned boundaries)
    float* ws    = (float*)d_ws;
    float* SD_J  = ws;                                   // 720
    float* Jt    = ws + 720;                             // 72 (+pad) -> 800
    float* G_ws  = ws + 800;                             // N*288
    float* w_t   = G_ws + (size_t)N * 288;               // 24*NVP
    float* jr_t  = w_t + 24 * NVP;                       // 24*NVP
    float* sd_t  = jr_t + 24 * NVP;                      // 30*NVP
    float* vt_t  = sd_t + 30 * NVP;                      // 3*NVP
    unsigned short* A_bf = (unsigned short*)(vt_t + 3 * NVP);       // 512*224
    unsigned short* B2   = A_bf + (size_t)512 * KDIM;               // 7*NT*512
    unsigned short* vpos = B2 + (size_t)7 * NT * 512;               // 512*NPRIME

    const int B2_N = 7 * NT * 16 * 32;
    int t_total = B2_N + (24 + 24 + 30 + 3) * NVP;
    t_pack<<<(t_total + 255) / 256, 256, 0, stream>>>(
        posedirs, weights, jointreg, shapedirs, v_templ,
        B2, w_t, jr_t, sd_t, vt_t);

    k1_regress<<<72, 256, 0, stream>>>(Jreg, sd_t, vt_t, SD_J, Jt);
    k2_fk<<<N, 64, 0, stream>>>(betas, thetas, SD_J, Jt, G_ws, A_bf);

    dim3 gg(NT / 12, N / 64);     // (108, 8)
    k3g<<<gg, 256, 0, stream>>>(A_bf, B2, vpos);

    dim3 gl(N / 4, NVP / 256);    // (128, 27) = 3456 blocks
    k3l<<<gl, 256, 0, stream>>>(trans, vpos, w_t, G_ws, out);

    float* outj = out + (size_t)N * NV * 3;
    k4_joints_t<<<N, 256, 0, stream>>>(out, jr_t, outj);
}

// Round 4
// 200.497 us; speedup vs baseline: 1.2506x; 1.1528x over previous
//
#include <hip/hip_runtime.h>
#include <hip/hip_bf16.h>
#include <math.h>

#define NJ 24
#define NV 6890
#define NVP 6912          // padded vertex count (27*256)
#define NPRIME 20736      // 3*NVP, GEMM N dimension
#define NT 1296           // NPRIME/16 n-tiles
#define KDIM 224          // padded K: [0..9]=betas/sd, [10]=1/vt, [11..217]=lrot/pd, rest 0

__constant__ int c_par[24] = {0, 0, 0, 0, 1, 2, 3, 4, 5, 6, 7, 8, 9, 9, 9,
                              12, 13, 14, 16, 17, 18, 19, 20, 21};

typedef __attribute__((ext_vector_type(8))) short short8;
typedef __attribute__((ext_vector_type(4))) float float4v;

__device__ __forceinline__ unsigned short f2b(float x) {
    __hip_bfloat16 h = __float2bfloat16(x);
    return *reinterpret_cast<unsigned short*>(&h);
}
__device__ __forceinline__ float b2f(unsigned short u) {
    unsigned int w = ((unsigned int)u) << 16;
    return __uint_as_float(w);
}

// ---------------------------------------------------------------------------
// T: pack kernel.  (sd_t/vt_t dropped — k1 reads raw sd/vt now)
__global__ void t_pack(const float* __restrict__ pd,
                       const float* __restrict__ W,
                       const float* __restrict__ jr,
                       const float* __restrict__ sd,
                       const float* __restrict__ vt,
                       unsigned short* __restrict__ B2,
                       float* __restrict__ w_t,
                       float* __restrict__ jr_t) {
    int idx = blockIdx.x * 256 + threadIdx.x;
    const int B2_N = 7 * NT * 16 * 32;        // 4,644,864
    if (idx < B2_N) {
        int kk = idx & 31;
        int ln = (idx >> 5) & 15;
        int rest = idx >> 9;                  // nt + NT*kc
        int nt = rest % NT, kc = rest / NT;
        int k = kc * 32 + kk;
        int np = nt * 16 + ln;
        int c = np / NVP, v = np - c * NVP;
        float val = 0.f;
        if (v < NV) {
            if (k < 10)       val = sd[(size_t)v * 30 + c * 10 + k];
            else if (k == 10) val = vt[v * 3 + c];
            else if (k < 218) val = pd[(size_t)v * 621 + c * 207 + (k - 11)];
        }
        B2[idx] = f2b(val);
        return;
    }
    idx -= B2_N;
    if (idx < 24 * NVP) {
        int j = idx / NVP, v = idx % NVP;
        if (v < NV) w_t[(size_t)j * NVP + v] = W[(size_t)v * 24 + j];
        return;
    }
    idx -= 24 * NVP;
    if (idx < 24 * NVP) {
        int j = idx / NVP, v = idx % NVP;
        if (v < NV) jr_t[(size_t)j * NVP + v] = jr[(size_t)v * 24 + j];
        return;
    }
}

// ---------------------------------------------------------------------------
// K1: fold J_regressor into shapedirs / v_template.
// RESTRUCTURED: was 72 blocks (0.28/CU, latency-bound).  Now grid (72, 8):
// each block reduces one vert-chunk of 864, reading RAW sd/vt (transpose
// dropped), writing partials SD_Jp[ch][72][11].  k2 sums the 8 chunks.
__global__ void k1_regress(const float* __restrict__ Jreg,
                           const float* __restrict__ sd,
                           const float* __restrict__ vt,
                           float* __restrict__ SD_Jp) {
    const int jc = blockIdx.x;            // 0..71
    const int ch = blockIdx.y;            // 0..7
    const int j = jc / 3, c = jc % 3;
    const int v0 = ch * 864;
    int vend = v0 + 864; if (vend > NV) vend = NV;

    float acc[11];
#pragma unroll
    for (int k = 0; k < 11; k++) acc[k] = 0.f;

    for (int v = v0 + threadIdx.x; v < vend; v += 256) {
        float r = Jreg[j * NV + v];
        const float* sp = sd + (size_t)v * 30 + c * 10;
#pragma unroll
        for (int k = 0; k < 10; k++) acc[k] += r * sp[k];
        acc[10] += r * vt[v * 3 + c];
    }
#pragma unroll
    for (int k = 0; k < 11; k++) {
        float x = acc[k];
        for (int off = 32; off > 0; off >>= 1) x += __shfl_down(x, off);
        acc[k] = x;
    }
    __shared__ float red[4][11];
    int lane = threadIdx.x & 63, wid = threadIdx.x >> 6;
    if (lane == 0) {
#pragma unroll
        for (int k = 0; k < 11; k++) red[wid][k] = acc[k];
    }
    __syncthreads();
    if (threadIdx.x == 0) {
        float* op = SD_Jp + ((size_t)ch * 72 + jc) * 11;
#pragma unroll
        for (int k = 0; k < 11; k++)
            op[k] = red[0][k] + red[1][k] + red[2][k] + red[3][k];
    }
}

// ---------------------------------------------------------------------------
// K2: per-sample joints + rodrigues + FK + A_bf pack.  grid = N, block = 64.
// Now also: sums SD_Jp partials (8 chunks) and zeroes outj[n] for k4's atomics.
__global__ void k2_fk(const float* __restrict__ betas,
                      const float* __restrict__ thetas,
                      const float* __restrict__ SD_Jp,
                      float* __restrict__ Gout,
                      unsigned short* __restrict__ A_bf,
                      float* __restrict__ outj) {
    int n = blockIdx.x;
    int j = threadIdx.x;

    __shared__ float bsh[10];
    __shared__ float Jl[24][3];
    __shared__ float A[24][12];
    __shared__ float Gs[24][12];
    __shared__ float lr[208];     // lrotmin staging for A_bf pack

    if (threadIdx.x < 10) bsh[threadIdx.x] = betas[n * 10 + threadIdx.x];
    if (threadIdx.x == 0) lr[207] = 0.f;
    // zero this sample's joint-output slice (k4 accumulates atomically)
    for (int q = threadIdx.x; q < 72; q += 64) outj[(size_t)n * 72 + q] = 0.f;
    __syncthreads();

    if (j < 24) {
#pragma unroll
        for (int c = 0; c < 3; c++) {
            float acc[11];
#pragma unroll
            for (int k = 0; k < 11; k++) acc[k] = 0.f;
#pragma unroll
            for (int ch = 0; ch < 8; ch++) {
                const float* pp = SD_Jp + ((size_t)ch * 72 + j * 3 + c) * 11;
#pragma unroll
                for (int k = 0; k < 11; k++) acc[k] += pp[k];
            }
            float s = acc[10];
#pragma unroll
            for (int k = 0; k < 10; k++) s += bsh[k] * acc[k];
            Jl[j][c] = s;
        }
    }
    __syncthreads();

    if (j < 24) {
        float rx = thetas[n * 72 + j * 3 + 0];
        float ry = thetas[n * 72 + j * 3 + 1];
        float rz = thetas[n * 72 + j * 3 + 2];
        float th = sqrtf(rx * rx + ry * ry + rz * rz) + 1e-8f;
        float inv = 1.f / th;
        float hx = rx * inv, hy = ry * inv, hz = rz * inv;
        float ct = cosf(th), st = sinf(th), omc = 1.f - ct;
        float R[3][3];
        R[0][0] = ct + omc * hx * hx;
        R[0][1] = omc * hx * hy - st * hz;
        R[0][2] = omc * hx * hz + st * hy;
        R[1][0] = omc * hx * hy + st * hz;
        R[1][1] = ct + omc * hy * hy;
        R[1][2] = omc * hy * hz - st * hx;
        R[2][0] = omc * hx * hz - st * hy;
        R[2][1] = omc * hy * hz + st * hx;
        R[2][2] = ct + omc * hz * hz;

        if (j >= 1) {
            float* lp = &lr[(j - 1) * 9];
#pragma unroll
            for (int r = 0; r < 3; r++)
#pragma unroll
                for (int c = 0; c < 3; c++)
                    lp[r * 3 + c] = R[r][c] - ((r == c) ? 1.f : 0.f);
        }
        float tx, ty, tz;
        if (j == 0) { tx = Jl[0][0]; ty = Jl[0][1]; tz = Jl[0][2]; }
        else {
            int p = c_par[j];
            tx = Jl[j][0] - Jl[p][0];
            ty = Jl[j][1] - Jl[p][1];
            tz = Jl[j][2] - Jl[p][2];
        }
#pragma unroll
        for (int r = 0; r < 3; r++) {
            A[j][r * 4 + 0] = R[r][0];
            A[j][r * 4 + 1] = R[r][1];
            A[j][r * 4 + 2] = R[r][2];
        }
        A[j][3] = tx; A[j][7] = ty; A[j][11] = tz;
    }
    __syncthreads();

    // lane 0: serial FK; all lanes: pack A_bf row from LDS (independent work)
    if (threadIdx.x == 0) {
#pragma unroll
        for (int q = 0; q < 12; q++) Gs[0][q] = A[0][q];
        for (int i = 1; i < 24; i++) {
            int p = c_par[i];
#pragma unroll
            for (int r = 0; r < 3; r++) {
                float g0 = Gs[p][r * 4 + 0], g1 = Gs[p][r * 4 + 1];
                float g2 = Gs[p][r * 4 + 2], g3 = Gs[p][r * 4 + 3];
#pragma unroll
                for (int c = 0; c < 4; c++) {
                    float s = g0 * A[i][0 * 4 + c] + g1 * A[i][1 * 4 + c] +
                              g2 * A[i][2 * 4 + c];
                    if (c == 3) s += g3;
                    Gs[i][r * 4 + c] = s;
                }
            }
        }
    }
    for (int k = threadIdx.x; k < KDIM; k += 64) {
        float val;
        if (k < 10)       val = bsh[k];
        else if (k == 10) val = 1.f;
        else if (k < 218) val = lr[k - 11];
        else              val = 0.f;
        A_bf[(size_t)n * KDIM + k] = f2b(val);
    }
    __syncthreads();

    if (j < 24) {
        float jx = Jl[j][0], jy = Jl[j][1], jz = Jl[j][2];
        float* gp = Gout + (size_t)n * 288 + j * 12;
#pragma unroll
        for (int r = 0; r < 3; r++) {
            float r0 = Gs[j][r * 4 + 0], r1 = Gs[j][r * 4 + 1];
            float r2 = Gs[j][r * 4 + 2], t = Gs[j][r * 4 + 3];
            gp[r * 4 + 0] = r0;
            gp[r * 4 + 1] = r1;
            gp[r * 4 + 2] = r2;
            gp[r * 4 + 3] = t - (r0 * jx + r1 * jy + r2 * jz);
        }
    }
}

// ---------------------------------------------------------------------------
// K3G: MFMA GEMM  (unchanged)
__global__ void __launch_bounds__(256)
k3g(const unsigned short* __restrict__ A_bf,
    const unsigned short* __restrict__ B2,
    unsigned short* __restrict__ vposed) {
    const int wave = threadIdx.x >> 6, lane = threadIdx.x & 63;
    const int ln = lane & 15, q = lane >> 4;
    const int m0 = blockIdx.y * 64 + wave * 16;
    const int nt0 = blockIdx.x * 12;

    short8 a[7];
    {
        const int row = m0 + ln;
#pragma unroll
        for (int kc = 0; kc < 7; kc++)
            a[kc] = *(const short8*)(A_bf + (size_t)row * KDIM + kc * 32 + q * 8);
    }
    for (int t = 0; t < 12; t++) {
        const int nt = nt0 + t;
        float4v acc = {0.f, 0.f, 0.f, 0.f};
#pragma unroll
        for (int kc = 0; kc < 7; kc++) {
            short8 b = *(const short8*)(B2 +
                (((size_t)kc * NT + nt) * 16 + ln) * 32 + q * 8);
            acc = __builtin_amdgcn_mfma_f32_16x16x32_bf16(a[kc], b, acc, 0, 0, 0);
        }
        const int np = nt * 16 + ln;
#pragma unroll
        for (int r = 0; r < 4; r++) {
            int m = m0 + q * 4 + r;
            vposed[(size_t)m * NPRIME + np] = f2b(acc[r]);
        }
    }
}

// ---------------------------------------------------------------------------
// K3L: LBS.  NO-LDS version: per-wave sample index hoisted to SGPR via
// readfirstlane; G / trans load through uniform (scalar) loads; waves fully
// independent, no __syncthreads.  grid (N/4, 27), block 256 = 4 waves.
__global__ void __launch_bounds__(256)
k3l(const float* __restrict__ trans,
    const unsigned short* __restrict__ vposed,
    const float* __restrict__ w_t,
    const float* __restrict__ G_ws,
    float* __restrict__ out) {
    const int tid = threadIdx.x;
    const int lane = tid & 63;
    const int nu = __builtin_amdgcn_readfirstlane(blockIdx.x * 4 + (tid >> 6));
    const int v4 = blockIdx.y * 256 + lane * 4;

    const float* gp = G_ws + (size_t)nu * 288;
    const float t0 = trans[nu * 3 + 0];
    const float t1 = trans[nu * 3 + 1];
    const float t2 = trans[nu * 3 + 2];

    float vp[3][4];
#pragma unroll
    for (int c = 0; c < 3; c++) {
        uint2 u = *(const uint2*)(vposed + (size_t)nu * NPRIME + c * NVP + v4);
        vp[c][0] = b2f((unsigned short)(u.x & 0xFFFF));
        vp[c][1] = b2f((unsigned short)(u.x >> 16));
        vp[c][2] = b2f((unsigned short)(u.y & 0xFFFF));
        vp[c][3] = b2f((unsigned short)(u.y >> 16));
    }

    float o[3][4];
#pragma unroll
    for (int c = 0; c < 3; c++)
#pragma unroll
        for (int i = 0; i < 4; i++) o[c][i] = 0.f;

    for (int j = 0; j < NJ; j++) {
        float4 w4 = *(const float4*)(w_t + (size_t)j * NVP + v4);
        float wv[4] = {w4.x, w4.y, w4.z, w4.w};
        const float4* g4 = (const float4*)(gp + j * 12);    // uniform loads
        float4 g0 = g4[0], g1 = g4[1], g2 = g4[2];
#pragma unroll
        for (int i = 0; i < 4; i++) {
            float x = vp[0][i], y = vp[1][i], z = vp[2][i];
            float r0 = g0.x * x + g0.y * y + g0.z * z + g0.w;
            float r1 = g1.x * x + g1.y * y + g1.z * z + g1.w;
            float r2 = g2.x * x + g2.y * y + g2.z * z + g2.w;
            o[0][i] += wv[i] * r0;
            o[1][i] += wv[i] * r1;
            o[2][i] += wv[i] * r2;
        }
    }

    {
        float* op = out + ((size_t)nu * NV + v4) * 3;
#pragma unroll
        for (int i = 0; i < 4; i++) {
            if (v4 + i < NV) {
                op[i * 3 + 0] = o[0][i] + t0;
                op[i * 3 + 1] = o[1][i] + t1;
                op[i * 3 + 2] = o[2][i] + t2;
            }
        }
    }
}

// ---------------------------------------------------------------------------
// K4: joints reduction.  RESTRUCTURED for TLP: grid (N, 4) = 2048 blocks
// (8/CU); each block handles a 1728-vert chunk, 4 waves x 6 joints; lane0
// atomicAdds 18 partials into outj (zeroed by k2 earlier in the iteration).
__global__ void __launch_bounds__(256)
k4_joints_t(const float* __restrict__ result,
            const float* __restrict__ jr_t,
            float* __restrict__ outj) {
    const int n = blockIdx.x;
    const int ch = blockIdx.y;
    const int wid = threadIdx.x >> 6, lane = threadIdx.x & 63;
    const int j0 = wid * 6;
    const int v0 = ch * 1728;
    int vend = v0 + 1728; if (vend > NV) vend = NV;

    float acc[18];
#pragma unroll
    for (int q = 0; q < 18; q++) acc[q] = 0.f;

    const float* rb = result + (size_t)n * NV * 3;
    for (int v = v0 + lane; v < vend; v += 64) {
        float r0 = rb[v * 3 + 0], r1 = rb[v * 3 + 1], r2 = rb[v * 3 + 2];
#pragma unroll
        for (int jj = 0; jj < 6; jj++) {
            float w = jr_t[(size_t)(j0 + jj) * NVP + v];
            acc[jj * 3 + 0] += w * r0;
            acc[jj * 3 + 1] += w * r1;
            acc[jj * 3 + 2] += w * r2;
        }
    }
#pragma unroll
    for (int q = 0; q < 18; q++) {
        float x = acc[q];
        for (int off = 32; off > 0; off >>= 1) x += __shfl_down(x, off);
        acc[q] = x;
    }
    if (lane == 0) {
#pragma unroll
        for (int q = 0; q < 18; q++)
            atomicAdd(&outj[(size_t)n * 72 + j0 * 3 + q], acc[q]);
    }
}

// ---------------------------------------------------------------------------
extern "C" void kernel_launch(void* const* d_in, const int* in_sizes, int n_in,
                              void* d_out, int out_size, void* d_ws, size_t ws_size,
                              hipStream_t stream) {
    const float* betas     = (const float*)d_in[0];
    const float* thetas    = (const float*)d_in[1];
    const float* trans     = (const float*)d_in[2];
    const float* v_templ   = (const float*)d_in[3];
    const float* shapedirs = (const float*)d_in[4];
    const float* posedirs  = (const float*)d_in[5];
    const float* Jreg      = (const float*)d_in[6];
    const float* jointreg  = (const float*)d_in[7];
    const float* weights   = (const float*)d_in[8];

    float* out = (float*)d_out;       // fp32: result [N,V,3] then joints [N,24,3]
    const int N = in_sizes[0] / 10;   // 512

    // ws layout
    float* ws    = (float*)d_ws;
    float* SD_Jp = ws;                                   // 8*72*11 = 6336 (+pad) -> 6400
    float* G_ws  = ws + 6400;                            // N*288
    float* w_t   = G_ws + (size_t)N * 288;               // 24*NVP
    float* jr_t  = w_t + 24 * NVP;                       // 24*NVP
    unsigned short* A_bf = (unsigned short*)(jr_t + 24 * NVP);      // 512*224
    unsigned short* B2   = A_bf + (size_t)512 * KDIM;               // 7*NT*512
    unsigned short* vpos = B2 + (size_t)7 * NT * 512;               // 512*NPRIME

    float* outj = out + (size_t)N * NV * 3;

    dim3 g1(72, 8);
    k1_regress<<<g1, 256, 0, stream>>>(Jreg, shapedirs, v_templ, SD_Jp);
    k2_fk<<<N, 64, 0, stream>>>(betas, thetas, SD_Jp, G_ws, A_bf, outj);

    const int B2_N = 7 * NT * 16 * 32;
    int t_total = B2_N + (24 + 24) * NVP;
    t_pack<<<(t_total + 255) / 256, 256, 0, stream>>>(
        posedirs, weights, jointreg, shapedirs, v_templ,
        B2, w_t, jr_t);

    dim3 gg(NT / 12, N / 64);     // (108, 8)
    k3g<<<gg, 256, 0, stream>>>(A_bf, B2, vpos);

    dim3 gl(N / 4, NVP / 256);    // (128, 27) = 3456 blocks
    k3l<<<gl, 256, 0, stream>>>(trans, vpos, w_t, G_ws, out);

    dim3 g4(N, 4);                // 2048 blocks
    k4_joints_t<<<g4, 256, 0, stream>>>(out, jr_t, outj);
}